// Round 13
// baseline (1198.732 us; speedup 1.0000x reference)
//
#include <hip/hip_runtime.h>

#define DEV __device__ __forceinline__
#define AS1 __attribute__((address_space(1)))
#define AS3 __attribute__((address_space(3)))

typedef __attribute__((ext_vector_type(4))) float f32x4;
typedef __attribute__((ext_vector_type(8))) short short8;

DEV float bf2f(unsigned short u) {
    union { unsigned int i; float f; } c;
    c.i = ((unsigned int)u) << 16;
    return c.f;
}
DEV unsigned short f2bf(float f) {
    union { float f; unsigned int i; } c;
    c.f = f;
    unsigned int u = c.i;
    u += 0x7FFFu + ((u >> 16) & 1u);   // RTNE (finite values only here)
    return (unsigned short)(u >> 16);
}

// ---------------------------------------------------------------------------
// wprep_k: 5 weight transposes W[K,256] -> WT[256][ldb] bf16 (contiguous dst).
// ---------------------------------------------------------------------------
__global__ void wprep_k(const float* __restrict__ W1, const float* __restrict__ W2,
                        const float* __restrict__ W3, const float* __restrict__ Wg1,
                        const float* __restrict__ Wg2,
                        unsigned short* __restrict__ WTbase,
                        int K1, int ldb1) {
    const int w1n   = 256 * ldb1;
    const int total = w1n + 4 * 65536;
    for (int idx = blockIdx.x * blockDim.x + threadIdx.x; idx < total;
         idx += gridDim.x * blockDim.x) {
        const float* W; int K, ldb, i;
        if (idx < w1n) { W = W1; K = K1; ldb = ldb1; i = idx; }
        else {
            int r = (idx - w1n) >> 16;
            i = (idx - w1n) & 65535;
            W = (r == 0) ? W2 : (r == 1) ? W3 : (r == 2) ? Wg1 : Wg2;
            K = 256; ldb = 256;
        }
        int n = i / ldb, k = i - n * ldb;
        WTbase[idx] = f2bf(k < K ? W[(size_t)k * 256 + n] : 0.f);
    }
}

// ---------------------------------------------------------------------------
// cvtx_k: x f32[M][K] -> xb bf16[M][Kp], zero-padded. DIVISION-FREE,
// wave-per-row: lane l handles groups l, l+64, ... of its row (contiguous
// 2KB wave reads, aligned 16B writes). Idempotent (dup-able for measurement).
// ---------------------------------------------------------------------------
__global__ void cvtx_k(const float* __restrict__ x, unsigned short* __restrict__ xb,
                       int M, int K, int Kp) {
    const int wpb  = blockDim.x >> 6;
    const int w0   = blockIdx.x * wpb + (threadIdx.x >> 6);
    const int lane = threadIdx.x & 63;
    const int gpr  = Kp >> 3;                  // 8-elem groups per row
    for (int row = w0; row < M; row += gridDim.x * wpb) {
        const float* src        = x + (size_t)row * K;
        unsigned short* dst     = xb + (size_t)row * Kp;
        for (int g = lane; g < gpr; g += 64) {
            const int k0 = g * 8;
            unsigned int wd[4];
            if (k0 + 8 <= K) {
                f32x4 v0 = *(const f32x4*)(src + k0);
                f32x4 v1 = *(const f32x4*)(src + k0 + 4);
                wd[0] = (unsigned int)f2bf(v0[0]) | ((unsigned int)f2bf(v0[1]) << 16);
                wd[1] = (unsigned int)f2bf(v0[2]) | ((unsigned int)f2bf(v0[3]) << 16);
                wd[2] = (unsigned int)f2bf(v1[0]) | ((unsigned int)f2bf(v1[1]) << 16);
                wd[3] = (unsigned int)f2bf(v1[2]) | ((unsigned int)f2bf(v1[3]) << 16);
            } else {
                unsigned short o[8];
                #pragma unroll
                for (int j = 0; j < 8; ++j)
                    o[j] = (k0 + j < K) ? f2bf(src[k0 + j]) : (unsigned short)0;
                wd[0] = o[0] | ((unsigned int)o[1] << 16);
                wd[1] = o[2] | ((unsigned int)o[3] << 16);
                wd[2] = o[4] | ((unsigned int)o[5] << 16);
                wd[3] = o[6] | ((unsigned int)o[7] << 16);
            }
            *(uint4*)(dst + k0) = *(uint4*)wd;
        }
    }
}

// ---------------------------------------------------------------------------
// Unified GEMM (round 10): BM=128, BN=256, BK=32, 8 waves, depth-2
// counted-vmcnt, 48 KB LDS -> 3 blocks/CU.
// ---------------------------------------------------------------------------
template<bool STATS, bool ADOT>
__launch_bounds__(512)
__global__ void gemm_k(const unsigned short* __restrict__ A,
                       const unsigned short* __restrict__ Bt,
                       unsigned short* __restrict__ C,
                       float* __restrict__ st,
                       const float* __restrict__ avs, const float* __restrict__ avd,
                       float* __restrict__ a_src, float* __restrict__ a_dst,
                       int M, int lda, int ldb, int ksteps)
{
    __shared__ __align__(16) unsigned short As[2][128 * 32];   // 2 x 8 KB
    __shared__ __align__(16) unsigned short Bs[2][256 * 32];   // 2 x 16 KB
    const int t    = threadIdx.x;
    const int wid  = t >> 6;       // 0..7
    const int lane = t & 63;
    const int wr   = wid >> 2;     // 0..1
    const int wc   = wid & 3;      // 0..3
    const int m0   = blockIdx.x * 128;

    f32x4 acc[4][4] = {};

    auto stage = [&](int buf, int ks) {
        const int k0 = ks * 32;
        {
            const int rr  = wid * 16 + (lane >> 2);
            const int csw = (lane & 3) ^ ((rr >> 1) & 3);
            __builtin_amdgcn_global_load_lds(
                (const AS1 void*)(A + (size_t)(m0 + rr) * lda + k0 + csw * 8),
                (AS3 void*)(&As[buf][wid * 16 * 32]), 16, 0, 0);
        }
        #pragma unroll
        for (int o = 0; o < 2; ++o) {
            const int rr  = wid * 32 + o * 16 + (lane >> 2);
            const int csw = (lane & 3) ^ ((rr >> 1) & 3);
            __builtin_amdgcn_global_load_lds(
                (const AS1 void*)(Bt + (size_t)rr * ldb + k0 + csw * 8),
                (AS3 void*)(&Bs[buf][(wid * 32 + o * 16) * 32]), 16, 0, 0);
        }
    };
    auto compute = [&](int buf) {
        short8 af[4], bfr[4];
        #pragma unroll
        for (int mi = 0; mi < 4; ++mi) {
            const int r   = wr * 64 + mi * 16 + (lane & 15);
            const int csw = (lane >> 4) ^ ((r >> 1) & 3);
            af[mi] = *(const short8*)(&As[buf][r * 32 + csw * 8]);
        }
        #pragma unroll
        for (int ni = 0; ni < 4; ++ni) {
            const int r   = wc * 64 + ni * 16 + (lane & 15);
            const int csw = (lane >> 4) ^ ((r >> 1) & 3);
            bfr[ni] = *(const short8*)(&Bs[buf][r * 32 + csw * 8]);
        }
        __builtin_amdgcn_s_setprio(1);
        #pragma unroll
        for (int mi = 0; mi < 4; ++mi)
            #pragma unroll
            for (int ni = 0; ni < 4; ++ni)
                acc[mi][ni] = __builtin_amdgcn_mfma_f32_16x16x32_bf16(
                    af[mi], bfr[ni], acc[mi][ni], 0, 0, 0);
        __builtin_amdgcn_s_setprio(0);
    };

    stage(0, 0);
    __builtin_amdgcn_sched_barrier(0);
    stage(1, 1);
    asm volatile("s_waitcnt vmcnt(3)" ::: "memory");
    __builtin_amdgcn_sched_barrier(0);
    __builtin_amdgcn_s_barrier();
    __builtin_amdgcn_sched_barrier(0);

    int cur = 0;
    for (int k = 0; k < ksteps; ++k) {
        compute(cur);
        if (k + 1 >= ksteps) break;
        __builtin_amdgcn_sched_barrier(0);
        __builtin_amdgcn_s_barrier();
        __builtin_amdgcn_sched_barrier(0);
        if (k + 2 < ksteps) {
            stage(cur, k + 2);
            asm volatile("s_waitcnt vmcnt(3)" ::: "memory");
        } else {
            asm volatile("s_waitcnt vmcnt(0)" ::: "memory");
        }
        __builtin_amdgcn_sched_barrier(0);
        __builtin_amdgcn_s_barrier();
        __builtin_amdgcn_sched_barrier(0);
        cur ^= 1;
    }

    #pragma unroll
    for (int mi = 0; mi < 4; ++mi) {
        #pragma unroll
        for (int ni = 0; ni < 4; ++ni) {
            const int col = wc * 64 + ni * 16 + (lane & 15);
            #pragma unroll
            for (int rg = 0; rg < 4; ++rg) {
                const int m = m0 + wr * 64 + mi * 16 + (lane >> 4) * 4 + rg;
                if (m < M)
                    C[(size_t)m * 256 + col] = f2bf(acc[mi][ni][rg]);
            }
        }
    }
    if constexpr (STATS) {
        #pragma unroll
        for (int ni = 0; ni < 4; ++ni) {
            float s = 0.f, q = 0.f;
            #pragma unroll
            for (int mi = 0; mi < 4; ++mi)
                #pragma unroll
                for (int rg = 0; rg < 4; ++rg) {
                    const int m = m0 + wr * 64 + mi * 16 + (lane >> 4) * 4 + rg;
                    const float v = (m < M) ? acc[mi][ni][rg] : 0.f;
                    s += v; q += v * v;
                }
            s += __shfl_xor(s, 16); q += __shfl_xor(q, 16);
            s += __shfl_xor(s, 32); q += __shfl_xor(q, 32);
            if (lane < 16) {
                const int col = wc * 64 + ni * 16 + lane;
                atomicAdd(&st[col], s);
                atomicAdd(&st[256 + col], q);
            }
        }
    }
    if constexpr (ADOT) {
        #pragma unroll
        for (int mi = 0; mi < 4; ++mi) {
            float ps[4] = {0.f, 0.f, 0.f, 0.f};
            float pd[4] = {0.f, 0.f, 0.f, 0.f};
            #pragma unroll
            for (int ni = 0; ni < 4; ++ni) {
                const int col = wc * 64 + ni * 16 + (lane & 15);
                const float a_s = avs[col], a_d = avd[col];
                #pragma unroll
                for (int rg = 0; rg < 4; ++rg) {
                    ps[rg] += acc[mi][ni][rg] * a_s;
                    pd[rg] += acc[mi][ni][rg] * a_d;
                }
            }
            #pragma unroll
            for (int rg = 0; rg < 4; ++rg) {
                #pragma unroll
                for (int off = 1; off < 16; off <<= 1) {
                    ps[rg] += __shfl_xor(ps[rg], off);
                    pd[rg] += __shfl_xor(pd[rg], off);
                }
                const int m = m0 + wr * 64 + mi * 16 + (lane >> 4) * 4 + rg;
                if ((lane & 15) == 0 && m < M) {
                    atomicAdd(&a_src[m], ps[rg]);
                    atomicAdd(&a_dst[m], pd[rg]);
                }
            }
        }
    }
}

// per-column sum & sumsq of bf16 h into st[0..255], st[256..511].
__global__ void colstats_k(const unsigned short* __restrict__ h, float* st, int total4) {
    const int gid    = blockIdx.x * 256 + threadIdx.x;
    const int stride = gridDim.x * 256;
    float4 s = {0.f, 0.f, 0.f, 0.f}, q = {0.f, 0.f, 0.f, 0.f};
    for (int i = gid; i < total4; i += stride) {
        ushort4 v = ((const ushort4*)h)[i];
        float x0 = bf2f(v.x), x1 = bf2f(v.y), x2 = bf2f(v.z), x3 = bf2f(v.w);
        s.x += x0; s.y += x1; s.z += x2; s.w += x3;
        q.x += x0 * x0; q.y += x1 * x1; q.z += x2 * x2; q.w += x3 * x3;
    }
    __shared__ float red[2][4][64][4];
    const int wid = threadIdx.x >> 6, lane = threadIdx.x & 63;
    *(float4*)&red[0][wid][lane][0] = s;
    *(float4*)&red[1][wid][lane][0] = q;
    __syncthreads();
    if (wid == 0) {
        float4 s0 = *(float4*)&red[0][0][lane][0];
        float4 q0 = *(float4*)&red[1][0][lane][0];
        #pragma unroll
        for (int w = 1; w < 4; ++w) {
            float4 sw = *(float4*)&red[0][w][lane][0];
            float4 qw = *(float4*)&red[1][w][lane][0];
            s0.x += sw.x; s0.y += sw.y; s0.z += sw.z; s0.w += sw.w;
            q0.x += qw.x; q0.y += qw.y; q0.z += qw.z; q0.w += qw.w;
        }
        atomicAdd(&st[lane * 4 + 0], s0.x);
        atomicAdd(&st[lane * 4 + 1], s0.y);
        atomicAdd(&st[lane * 4 + 2], s0.z);
        atomicAdd(&st[lane * 4 + 3], s0.w);
        atomicAdd(&st[256 + lane * 4 + 0], q0.x);
        atomicAdd(&st[256 + lane * 4 + 1], q0.y);
        atomicAdd(&st[256 + lane * 4 + 2], q0.z);
        atomicAdd(&st[256 + lane * 4 + 3], q0.w);
    }
}

// Fused BN-finalize + BN-apply + ELU.
template<bool OUT_F32>
__global__ void bnelu_k(const unsigned short* __restrict__ h,
                        const float* __restrict__ st, const float* __restrict__ g,
                        const float* __restrict__ be, void* __restrict__ outp,
                        int total4, float invN) {
    const int gid    = blockIdx.x * 256 + threadIdx.x;
    const int stride = gridDim.x * 256;
    const int c      = (gid << 2) & 255;
    float sc[4], sh[4];
    #pragma unroll
    for (int j = 0; j < 4; ++j) {
        float mu  = st[c + j] * invN;
        float var = st[256 + c + j] * invN - mu * mu;
        float s   = g[c + j] * rsqrtf(var + 1e-5f);
        sc[j] = s;
        sh[j] = be[c + j] - mu * s;
    }
    for (int i = gid; i < total4; i += stride) {
        ushort4 v = ((const ushort4*)h)[i];
        float y0 = fmaf(bf2f(v.x), sc[0], sh[0]);
        float y1 = fmaf(bf2f(v.y), sc[1], sh[1]);
        float y2 = fmaf(bf2f(v.z), sc[2], sh[2]);
        float y3 = fmaf(bf2f(v.w), sc[3], sh[3]);
        y0 = y0 > 0.f ? y0 : expm1f(y0);
        y1 = y1 > 0.f ? y1 : expm1f(y1);
        y2 = y2 > 0.f ? y2 : expm1f(y2);
        y3 = y3 > 0.f ? y3 : expm1f(y3);
        if (OUT_F32) {
            float4 o; o.x = y0; o.y = y1; o.z = y2; o.w = y3;
            ((float4*)outp)[i] = o;
        } else {
            ushort4 o;
            o.x = f2bf(y0); o.y = f2bf(y1); o.z = f2bf(y2); o.w = f2bf(y3);
            ((ushort4*)outp)[i] = o;
        }
    }
}

DEV float lrelu(float e) { return e > 0.f ? e : 0.2f * e; }

// one wave per destination node: online max+sum, then x4-unrolled gather.
__global__ void gat_k(const unsigned short* __restrict__ xl, const float* __restrict__ a_src,
                      const float* __restrict__ a_dst, const int* __restrict__ csr,
                      const int* __restrict__ indptr, unsigned short* __restrict__ out, int N) {
    int d = (blockIdx.x * blockDim.x + threadIdx.x) >> 6;
    int lane = threadIdx.x & 63;
    if (d >= N) return;
    int beg = indptr[d], end = indptr[d + 1];
    float adst = a_dst[d];

    float m = -1e30f, s = 0.f;
    for (int i = beg + lane; i < end; i += 64) {
        float e  = lrelu(a_src[csr[i]] + adst);
        float nm = fmaxf(m, e);
        s = s * __expf(m - nm) + __expf(e - nm);
        m = nm;
    }
    float mx = m;
    #pragma unroll
    for (int off = 32; off; off >>= 1) mx = fmaxf(mx, __shfl_xor(mx, off));
    s *= __expf(m - mx);
    #pragma unroll
    for (int off = 32; off; off >>= 1) s += __shfl_xor(s, off);
    float inv = 1.f / (s + 1e-16f);

    float4 A0 = {0,0,0,0}, A1 = {0,0,0,0}, A2 = {0,0,0,0}, A3 = {0,0,0,0};
    int i = beg;
    for (; i + 4 <= end; i += 4) {
        int s0 = csr[i], s1 = csr[i+1], s2 = csr[i+2], s3 = csr[i+3];
        float w0 = __expf(lrelu(a_src[s0] + adst) - mx) * inv;
        float w1 = __expf(lrelu(a_src[s1] + adst) - mx) * inv;
        float w2 = __expf(lrelu(a_src[s2] + adst) - mx) * inv;
        float w3 = __expf(lrelu(a_src[s3] + adst) - mx) * inv;
        ushort4 v0 = *(const ushort4*)(xl + (size_t)s0 * 256 + lane * 4);
        ushort4 v1 = *(const ushort4*)(xl + (size_t)s1 * 256 + lane * 4);
        ushort4 v2 = *(const ushort4*)(xl + (size_t)s2 * 256 + lane * 4);
        ushort4 v3 = *(const ushort4*)(xl + (size_t)s3 * 256 + lane * 4);
        A0.x += w0 * bf2f(v0.x); A0.y += w0 * bf2f(v0.y); A0.z += w0 * bf2f(v0.z); A0.w += w0 * bf2f(v0.w);
        A1.x += w1 * bf2f(v1.x); A1.y += w1 * bf2f(v1.y); A1.z += w1 * bf2f(v1.z); A1.w += w1 * bf2f(v1.w);
        A2.x += w2 * bf2f(v2.x); A2.y += w2 * bf2f(v2.y); A2.z += w2 * bf2f(v2.z); A2.w += w2 * bf2f(v2.w);
        A3.x += w3 * bf2f(v3.x); A3.y += w3 * bf2f(v3.y); A3.z += w3 * bf2f(v3.z); A3.w += w3 * bf2f(v3.w);
    }
    for (; i < end; ++i) {
        int sidx = csr[i];
        float w = __expf(lrelu(a_src[sidx] + adst) - mx) * inv;
        ushort4 v = *(const ushort4*)(xl + (size_t)sidx * 256 + lane * 4);
        A0.x += w * bf2f(v.x); A0.y += w * bf2f(v.y);
        A0.z += w * bf2f(v.z); A0.w += w * bf2f(v.w);
    }
    ushort4 o;
    o.x = f2bf(A0.x + A1.x + A2.x + A3.x);
    o.y = f2bf(A0.y + A1.y + A2.y + A3.y);
    o.z = f2bf(A0.z + A1.z + A2.z + A3.z);
    o.w = f2bf(A0.w + A1.w + A2.w + A3.w);
    *(ushort4*)(out + (size_t)d * 256 + lane * 4) = o;
}

// ---- CSR build ----
__global__ void hist_k(const int* __restrict__ edges, int* deg, int E, int N) {
    int total = E + N;
    for (int i = blockIdx.x * blockDim.x + threadIdx.x; i < total;
         i += gridDim.x * blockDim.x) {
        int dd = (i < E) ? edges[E + i] : (i - E);
        atomicAdd(&deg[dd], 1);
    }
}

__global__ void scan1_k(const int* __restrict__ deg, int* iscan, int* bsum, int N) {
    int i = blockIdx.x * 256 + threadIdx.x;
    int lane = threadIdx.x & 63, wid = threadIdx.x >> 6;
    int v = (i < N) ? deg[i] : 0;
    #pragma unroll
    for (int off = 1; off < 64; off <<= 1) {
        int u = __shfl_up(v, off);
        if (lane >= off) v += u;
    }
    __shared__ int wsum[4];
    if (lane == 63) wsum[wid] = v;
    __syncthreads();
    #pragma unroll
    for (int w = 0; w < 3; ++w) if (wid > w) v += wsum[w];
    if (i < N) iscan[i] = v;
    if (threadIdx.x == 255) bsum[blockIdx.x] = v;
}

__global__ void scan2_k(int* bsum, int nb) {
    int t = threadIdx.x;
    int lane = t & 63, wid = t >> 6;
    int v = (t < nb) ? bsum[t] : 0;
    int orig = v;
    #pragma unroll
    for (int off = 1; off < 64; off <<= 1) {
        int u = __shfl_up(v, off);
        if (lane >= off) v += u;
    }
    __shared__ int wsum[4];
    if (lane == 63) wsum[wid] = v;
    __syncthreads();
    #pragma unroll
    for (int w = 0; w < 3; ++w) if (wid > w) v += wsum[w];
    if (t < nb) bsum[t] = v - orig;
}

__global__ void scan3copy_k(const int* __restrict__ iscan, const int* __restrict__ boff,
                            const int* __restrict__ deg, int* indptr, int* pos, int N) {
    int i = blockIdx.x * 256 + threadIdx.x;
    if (i < N) {
        int v = iscan[i] + boff[blockIdx.x];
        indptr[i + 1] = v;
        pos[i] = v - deg[i];
    }
    if (i == 0) indptr[0] = 0;
}

__global__ void scatter_k(const int* __restrict__ edges, int* pos, int* csr, int E, int N) {
    int total = E + N;
    for (int i = blockIdx.x * blockDim.x + threadIdx.x; i < total;
         i += gridDim.x * blockDim.x) {
        int s  = (i < E) ? edges[i]     : (i - E);
        int dd = (i < E) ? edges[E + i] : (i - E);
        int slot = atomicAdd(&pos[dd], 1);
        csr[slot] = s;
    }
}

// ---------------------------------------------------------------------------
extern "C" void kernel_launch(void* const* d_in, const int* in_sizes, int n_in,
                              void* d_out, int out_size, void* d_ws, size_t ws_size,
                              hipStream_t stream) {
    const float* x     = (const float*)d_in[0];
    const int*   edges = (const int*)d_in[1];
    const float* W1 = (const float*)d_in[2];
    const float* W2 = (const float*)d_in[4];
    const float* W3 = (const float*)d_in[6];
    const float* g1 = (const float*)d_in[8],  *be1 = (const float*)d_in[9];
    const float* g2 = (const float*)d_in[10], *be2 = (const float*)d_in[11];
    const float* g3 = (const float*)d_in[12], *be3 = (const float*)d_in[13];
    const float* Wg1 = (const float*)d_in[14];
    const float* as1 = (const float*)d_in[15], *ad1 = (const float*)d_in[16];
    const float* g4 = (const float*)d_in[18], *be4 = (const float*)d_in[19];
    const float* Wg2 = (const float*)d_in[20];
    const float* as2 = (const float*)d_in[21], *ad2 = (const float*)d_in[22];
    const float* g5 = (const float*)d_in[24], *be5 = (const float*)d_in[25];

    const int N    = out_size / 256;
    const int K1   = in_sizes[0] / N;
    const int E    = in_sizes[1] / 2;
    const int Etot = E + N;
    const int ks1  = (K1 + 63) / 64;
    const int ldb1 = ks1 * 64;                // padded K (2624), 32 | ldb1

    // workspace carve (256B aligned)
    char* p = (char*)d_ws;
    auto alloc = [&](size_t bytes) {
        char* r = p;
        p += (bytes + 255) & ~(size_t)255;
        return r;
    };
    unsigned short* W1T  = (unsigned short*)alloc((size_t)256 * ldb1 * 2);
    unsigned short* W2T  = (unsigned short*)alloc(256 * 256 * 2);
    unsigned short* W3T  = (unsigned short*)alloc(256 * 256 * 2);
    unsigned short* Wg1T = (unsigned short*)alloc(256 * 256 * 2);
    unsigned short* Wg2T = (unsigned short*)alloc(256 * 256 * 2);
    unsigned short* xb   = (unsigned short*)alloc((size_t)N * ldb1 * 2);
    unsigned short* ha   = (unsigned short*)alloc((size_t)N * 256 * 2);
    unsigned short* hb   = (unsigned short*)alloc((size_t)N * 256 * 2);
    unsigned short* xl   = (unsigned short*)alloc((size_t)N * 256 * 2);
    char* zero_base = p;
    int*   deg    = (int*)alloc((size_t)N * 4);
    float* st     = (float*)alloc(5 * 512 * 4);
    float* asrc1  = (float*)alloc((size_t)N * 4);
    float* adst1  = (float*)alloc((size_t)N * 4);
    float* asrc2  = (float*)alloc((size_t)N * 4);
    float* adst2  = (float*)alloc((size_t)N * 4);
    size_t zero_bytes = (size_t)(p - zero_base);
    int*   iscan  = (int*)alloc((size_t)N * 4);
    int*   bsum   = (int*)alloc(1024);
    int*   indptr = (int*)alloc((size_t)(N + 1) * 4);
    int*   pos    = (int*)alloc((size_t)N * 4);
    int*   csr    = (int*)alloc((size_t)Etot * 4);
    (void)alloc(1 << 19);   // tail guard (benign OOB reads of last tile rows)
    float* out = (float*)d_out;

    const int nb = (N + 255) / 256;
    const int eg = (Etot + 255) / 256;
    const int gb = (N + 127) / 128;           // 391 blocks, 48KB LDS -> 3/CU
    const int t4 = N * 64;
    const float invN = 1.f / (float)N;

    hipMemsetAsync(zero_base, 0, zero_bytes, stream);

    // ---- graph CSR ----
    hist_k<<<eg, 256, 0, stream>>>(edges, deg, E, N);
    scan1_k<<<nb, 256, 0, stream>>>(deg, iscan, bsum, N);
    scan2_k<<<1, 256, 0, stream>>>(bsum, nb);
    scan3copy_k<<<nb, 256, 0, stream>>>(iscan, bsum, deg, indptr, pos, N);
    scatter_k<<<eg, 256, 0, stream>>>(edges, pos, csr, E, N);

    // ---- weight prep ----
    wprep_k<<<512, 256, 0, stream>>>(W1, W2, W3, Wg1, Wg2, W1T, K1, ldb1);

    // ---- x conversion (division-free, wave-per-row) + 2 MEASUREMENT DUPS ----
    cvtx_k<<<2048, 256, 0, stream>>>(x, xb, N, K1, ldb1);
    cvtx_k<<<2048, 256, 0, stream>>>(x, xb, N, K1, ldb1);   // dup (idempotent)
    cvtx_k<<<2048, 256, 0, stream>>>(x, xb, N, K1, ldb1);   // dup (idempotent)

    // ---- layer 1: GEMM (+stats) -> BN+ELU ----
    gemm_k<true, false><<<gb, 512, 0, stream>>>(xb, W1T, ha, st, nullptr, nullptr,
                                                nullptr, nullptr, N, ldb1, ldb1, ldb1 / 32);
    bnelu_k<false><<<2048, 256, 0, stream>>>(ha, st, g1, be1, ha, t4, invN);

    // ---- layers 2,3 ----
    gemm_k<true, false><<<gb, 512, 0, stream>>>(ha, W2T, hb, st + 512, nullptr, nullptr,
                                                nullptr, nullptr, N, 256, 256, 8);
    bnelu_k<false><<<2048, 256, 0, stream>>>(hb, st + 512, g2, be2, hb, t4, invN);

    gemm_k<true, false><<<gb, 512, 0, stream>>>(hb, W3T, ha, st + 1024, nullptr, nullptr,
                                                nullptr, nullptr, N, 256, 256, 8);
    bnelu_k<false><<<2048, 256, 0, stream>>>(ha, st + 1024, g3, be3, ha, t4, invN);

    // ---- GAT layer 1 (adot fused into GEMM epilogue) ----
    gemm_k<false, true><<<gb, 512, 0, stream>>>(ha, Wg1T, xl, nullptr, as1, ad1,
                                                asrc1, adst1, N, 256, 256, 8);
    gat_k<<<(N + 3) / 4, 256, 0, stream>>>(xl, asrc1, adst1, csr, indptr, hb, N);
    colstats_k<<<1024, 256, 0, stream>>>(hb, st + 1536, t4);
    bnelu_k<false><<<2048, 256, 0, stream>>>(hb, st + 1536, g4, be4, hb, t4, invN);

    // ---- GAT layer 2 ----
    gemm_k<false, true><<<gb, 512, 0, stream>>>(hb, Wg2T, xl, nullptr, as2, ad2,
                                                asrc2, adst2, N, 256, 256, 8);
    gat_k<<<(N + 3) / 4, 256, 0, stream>>>(xl, asrc2, adst2, csr, indptr, ha, N);
    colstats_k<<<1024, 256, 0, stream>>>(ha, st + 2048, t4);
    bnelu_k<true><<<2048, 256, 0, stream>>>(ha, st + 2048, g5, be5, out, t4, invN);
}

// Round 14
// 958.977 us; speedup vs baseline: 1.2500x; 1.2500x over previous
//
#include <hip/hip_runtime.h>

#define DEV __device__ __forceinline__
#define AS1 __attribute__((address_space(1)))
#define AS3 __attribute__((address_space(3)))

typedef __attribute__((ext_vector_type(4))) float f32x4;
typedef __attribute__((ext_vector_type(8))) short short8;

DEV float bf2f(unsigned short u) {
    union { unsigned int i; float f; } c;
    c.i = ((unsigned int)u) << 16;
    return c.f;
}
DEV unsigned short f2bf(float f) {
    union { float f; unsigned int i; } c;
    c.f = f;
    unsigned int u = c.i;
    u += 0x7FFFu + ((u >> 16) & 1u);   // RTNE (finite values only here)
    return (unsigned short)(u >> 16);
}

// ---------------------------------------------------------------------------
// wprep_k: 5 weight transposes W[K,256] -> WT[256][ldb] bf16 (contiguous dst).
// ---------------------------------------------------------------------------
__global__ void wprep_k(const float* __restrict__ W1, const float* __restrict__ W2,
                        const float* __restrict__ W3, const float* __restrict__ Wg1,
                        const float* __restrict__ Wg2,
                        unsigned short* __restrict__ WTbase,
                        int K1, int ldb1) {
    const int w1n   = 256 * ldb1;
    const int total = w1n + 4 * 65536;
    for (int idx = blockIdx.x * blockDim.x + threadIdx.x; idx < total;
         idx += gridDim.x * blockDim.x) {
        const float* W; int K, ldb, i;
        if (idx < w1n) { W = W1; K = K1; ldb = ldb1; i = idx; }
        else {
            int r = (idx - w1n) >> 16;
            i = (idx - w1n) & 65535;
            W = (r == 0) ? W2 : (r == 1) ? W3 : (r == 2) ? Wg1 : Wg2;
            K = 256; ldb = 256;
        }
        int n = i / ldb, k = i - n * ldb;
        WTbase[idx] = f2bf(k < K ? W[(size_t)k * 256 + n] : 0.f);
    }
}

// ---------------------------------------------------------------------------
// gemm1f_k (layer 1): C[M,256] = f32 X[M][K] @ B; conversion FUSED.
// BM=128, BN=256, BK=32, 512 threads = 8 waves (2x4), 64x64 tile/wave.
// A path: reg-staged (each thread 8 f32 of one row: 2 dwordx4), cvt+swizzled
// ds_write_b128 AFTER the counted wait (T14 split). B via global_load_lds.
// 4 vmem ops per wave per tile (2 B-lds + 2 X-reg) -> s_waitcnt vmcnt(4).
// LDS 48 KB -> 3 blocks/CU. Clamped X offsets stay inside x (finite values
// x zero-padded B rows = 0). Fused BN column stats.
// ---------------------------------------------------------------------------
__launch_bounds__(512)
__global__ void gemm1f_k(const float* __restrict__ X,
                         const unsigned short* __restrict__ Bt,
                         unsigned short* __restrict__ C,
                         float* __restrict__ st,
                         int M, int K, int ldb, int ksteps)
{
    __shared__ __align__(16) unsigned short As[2][128 * 32];   // 2 x 8 KB
    __shared__ __align__(16) unsigned short Bs[2][256 * 32];   // 2 x 16 KB
    const int t    = threadIdx.x;
    const int wid  = t >> 6;
    const int lane = t & 63;
    const int wr   = wid >> 2;
    const int wc   = wid & 3;
    const int m0   = blockIdx.x * 128;
    const int arow = t >> 2;           // 0..127
    const int acol = (t & 3) * 8;      // 8-float group within 32-col tile
    const size_t maxoff = (size_t)M * (size_t)K - 8;

    f32x4 acc[4][4] = {};
    float arA[8], arB[8];              // X reg staging (static names, rule #20)

    auto stageB = [&](int buf, int ks) {           // 2 gload_lds per wave
        const int k0 = ks * 32;
        #pragma unroll
        for (int o = 0; o < 2; ++o) {
            const int rr  = wid * 32 + o * 16 + (lane >> 2);
            const int csw = (lane & 3) ^ ((rr >> 1) & 3);
            __builtin_amdgcn_global_load_lds(
                (const AS1 void*)(Bt + (size_t)rr * ldb + k0 + csw * 8),
                (AS3 void*)(&Bs[buf][(wid * 32 + o * 16) * 32]), 16, 0, 0);
        }
    };
    auto loadX = [&](int ks, float (&ar)[8]) {     // 2 dwordx4 per thread
        size_t off = (size_t)(m0 + arow) * K + (size_t)(ks * 32 + acol);
        off = off < maxoff ? off : maxoff;         // finite garbage x 0-B = 0
        *(f32x4*)&ar[0] = *(const f32x4*)(X + off);
        *(f32x4*)&ar[4] = *(const f32x4*)(X + off + 4);
    };
    auto writeA = [&](int buf, float (&ar)[8]) {   // cvt + swizzled b128 write
        const int csw = (t & 3) ^ ((arow >> 1) & 3);
        unsigned int wd[4];
        wd[0] = (unsigned int)f2bf(ar[0]) | ((unsigned int)f2bf(ar[1]) << 16);
        wd[1] = (unsigned int)f2bf(ar[2]) | ((unsigned int)f2bf(ar[3]) << 16);
        wd[2] = (unsigned int)f2bf(ar[4]) | ((unsigned int)f2bf(ar[5]) << 16);
        wd[3] = (unsigned int)f2bf(ar[6]) | ((unsigned int)f2bf(ar[7]) << 16);
        *(uint4*)&As[buf][arow * 32 + csw * 8] = *(uint4*)wd;
    };
    auto compute = [&](int buf) {
        short8 af[4], bfr[4];
        #pragma unroll
        for (int mi = 0; mi < 4; ++mi) {
            const int r   = wr * 64 + mi * 16 + (lane & 15);
            const int csw = (lane >> 4) ^ ((r >> 1) & 3);
            af[mi] = *(const short8*)(&As[buf][r * 32 + csw * 8]);
        }
        #pragma unroll
        for (int ni = 0; ni < 4; ++ni) {
            const int r   = wc * 64 + ni * 16 + (lane & 15);
            const int csw = (lane >> 4) ^ ((r >> 1) & 3);
            bfr[ni] = *(const short8*)(&Bs[buf][r * 32 + csw * 8]);
        }
        __builtin_amdgcn_s_setprio(1);
        #pragma unroll
        for (int mi = 0; mi < 4; ++mi)
            #pragma unroll
            for (int ni = 0; ni < 4; ++ni)
                acc[mi][ni] = __builtin_amdgcn_mfma_f32_16x16x32_bf16(
                    af[mi], bfr[ni], acc[mi][ni], 0, 0, 0);
        __builtin_amdgcn_s_setprio(0);
    };

    // ---- prologue: tiles 0,1 in flight ----
    stageB(0, 0); loadX(0, arA);
    __builtin_amdgcn_sched_barrier(0);
    stageB(1, 1); loadX(1, arB);
    asm volatile("s_waitcnt vmcnt(4)" ::: "memory");   // B0 + X0 landed
    __builtin_amdgcn_sched_barrier(0);
    writeA(0, arA);
    asm volatile("s_waitcnt lgkmcnt(0)" ::: "memory");
    __builtin_amdgcn_sched_barrier(0);
    __builtin_amdgcn_s_barrier();
    __builtin_amdgcn_sched_barrier(0);

    // ---- main loop ----
    int cur = 0;
    for (int k = 0; k < ksteps; ++k) {
        compute(cur);                                  // tile k
        if (k + 1 >= ksteps) break;
        __builtin_amdgcn_sched_barrier(0);
        __builtin_amdgcn_s_barrier();                  // buf[cur] free
        __builtin_amdgcn_sched_barrier(0);
        if (k + 2 < ksteps) {
            stageB(cur, k + 2);
            if (k & 1) loadX(k + 2, arB); else loadX(k + 2, arA);
            asm volatile("s_waitcnt vmcnt(4)" ::: "memory");  // tile k+1 landed
        } else {
            asm volatile("s_waitcnt vmcnt(0)" ::: "memory");
        }
        __builtin_amdgcn_sched_barrier(0);
        if (k & 1) writeA(cur ^ 1, arA); else writeA(cur ^ 1, arB);
        asm volatile("s_waitcnt lgkmcnt(0)" ::: "memory");
        __builtin_amdgcn_sched_barrier(0);
        __builtin_amdgcn_s_barrier();                  // buf[cur^1] ready
        __builtin_amdgcn_sched_barrier(0);
        cur ^= 1;
    }

    // ---- epilogue: bf16 C + fused BN stats ----
    #pragma unroll
    for (int mi = 0; mi < 4; ++mi) {
        #pragma unroll
        for (int ni = 0; ni < 4; ++ni) {
            const int col = wc * 64 + ni * 16 + (lane & 15);
            #pragma unroll
            for (int rg = 0; rg < 4; ++rg) {
                const int m = m0 + wr * 64 + mi * 16 + (lane >> 4) * 4 + rg;
                if (m < M)
                    C[(size_t)m * 256 + col] = f2bf(acc[mi][ni][rg]);
            }
        }
    }
    #pragma unroll
    for (int ni = 0; ni < 4; ++ni) {
        float s = 0.f, q = 0.f;
        #pragma unroll
        for (int mi = 0; mi < 4; ++mi)
            #pragma unroll
            for (int rg = 0; rg < 4; ++rg) {
                const int m = m0 + wr * 64 + mi * 16 + (lane >> 4) * 4 + rg;
                const float v = (m < M) ? acc[mi][ni][rg] : 0.f;
                s += v; q += v * v;
            }
        s += __shfl_xor(s, 16); q += __shfl_xor(q, 16);
        s += __shfl_xor(s, 32); q += __shfl_xor(q, 32);
        if (lane < 16) {
            const int col = wc * 64 + ni * 16 + lane;
            atomicAdd(&st[col], s);
            atomicAdd(&st[256 + col], q);
        }
    }
}

// ---------------------------------------------------------------------------
// Unified bf16 GEMM (round 10): BM=128, BN=256, BK=32, 8 waves, depth-2
// counted-vmcnt, 48 KB LDS -> 3 blocks/CU.
// ---------------------------------------------------------------------------
template<bool STATS, bool ADOT>
__launch_bounds__(512)
__global__ void gemm_k(const unsigned short* __restrict__ A,
                       const unsigned short* __restrict__ Bt,
                       unsigned short* __restrict__ C,
                       float* __restrict__ st,
                       const float* __restrict__ avs, const float* __restrict__ avd,
                       float* __restrict__ a_src, float* __restrict__ a_dst,
                       int M, int lda, int ldb, int ksteps)
{
    __shared__ __align__(16) unsigned short As[2][128 * 32];   // 2 x 8 KB
    __shared__ __align__(16) unsigned short Bs[2][256 * 32];   // 2 x 16 KB
    const int t    = threadIdx.x;
    const int wid  = t >> 6;       // 0..7
    const int lane = t & 63;
    const int wr   = wid >> 2;     // 0..1
    const int wc   = wid & 3;      // 0..3
    const int m0   = blockIdx.x * 128;

    f32x4 acc[4][4] = {};

    auto stage = [&](int buf, int ks) {
        const int k0 = ks * 32;
        {
            const int rr  = wid * 16 + (lane >> 2);
            const int csw = (lane & 3) ^ ((rr >> 1) & 3);
            __builtin_amdgcn_global_load_lds(
                (const AS1 void*)(A + (size_t)(m0 + rr) * lda + k0 + csw * 8),
                (AS3 void*)(&As[buf][wid * 16 * 32]), 16, 0, 0);
        }
        #pragma unroll
        for (int o = 0; o < 2; ++o) {
            const int rr  = wid * 32 + o * 16 + (lane >> 2);
            const int csw = (lane & 3) ^ ((rr >> 1) & 3);
            __builtin_amdgcn_global_load_lds(
                (const AS1 void*)(Bt + (size_t)rr * ldb + k0 + csw * 8),
                (AS3 void*)(&Bs[buf][(wid * 32 + o * 16) * 32]), 16, 0, 0);
        }
    };
    auto compute = [&](int buf) {
        short8 af[4], bfr[4];
        #pragma unroll
        for (int mi = 0; mi < 4; ++mi) {
            const int r   = wr * 64 + mi * 16 + (lane & 15);
            const int csw = (lane >> 4) ^ ((r >> 1) & 3);
            af[mi] = *(const short8*)(&As[buf][r * 32 + csw * 8]);
        }
        #pragma unroll
        for (int ni = 0; ni < 4; ++ni) {
            const int r   = wc * 64 + ni * 16 + (lane & 15);
            const int csw = (lane >> 4) ^ ((r >> 1) & 3);
            bfr[ni] = *(const short8*)(&Bs[buf][r * 32 + csw * 8]);
        }
        __builtin_amdgcn_s_setprio(1);
        #pragma unroll
        for (int mi = 0; mi < 4; ++mi)
            #pragma unroll
            for (int ni = 0; ni < 4; ++ni)
                acc[mi][ni] = __builtin_amdgcn_mfma_f32_16x16x32_bf16(
                    af[mi], bfr[ni], acc[mi][ni], 0, 0, 0);
        __builtin_amdgcn_s_setprio(0);
    };

    stage(0, 0);
    __builtin_amdgcn_sched_barrier(0);
    stage(1, 1);
    asm volatile("s_waitcnt vmcnt(3)" ::: "memory");
    __builtin_amdgcn_sched_barrier(0);
    __builtin_amdgcn_s_barrier();
    __builtin_amdgcn_sched_barrier(0);

    int cur = 0;
    for (int k = 0; k < ksteps; ++k) {
        compute(cur);
        if (k + 1 >= ksteps) break;
        __builtin_amdgcn_sched_barrier(0);
        __builtin_amdgcn_s_barrier();
        __builtin_amdgcn_sched_barrier(0);
        if (k + 2 < ksteps) {
            stage(cur, k + 2);
            asm volatile("s_waitcnt vmcnt(3)" ::: "memory");
        } else {
            asm volatile("s_waitcnt vmcnt(0)" ::: "memory");
        }
        __builtin_amdgcn_sched_barrier(0);
        __builtin_amdgcn_s_barrier();
        __builtin_amdgcn_sched_barrier(0);
        cur ^= 1;
    }

    #pragma unroll
    for (int mi = 0; mi < 4; ++mi) {
        #pragma unroll
        for (int ni = 0; ni < 4; ++ni) {
            const int col = wc * 64 + ni * 16 + (lane & 15);
            #pragma unroll
            for (int rg = 0; rg < 4; ++rg) {
                const int m = m0 + wr * 64 + mi * 16 + (lane >> 4) * 4 + rg;
                if (m < M)
                    C[(size_t)m * 256 + col] = f2bf(acc[mi][ni][rg]);
            }
        }
    }
    if constexpr (STATS) {
        #pragma unroll
        for (int ni = 0; ni < 4; ++ni) {
            float s = 0.f, q = 0.f;
            #pragma unroll
            for (int mi = 0; mi < 4; ++mi)
                #pragma unroll
                for (int rg = 0; rg < 4; ++rg) {
                    const int m = m0 + wr * 64 + mi * 16 + (lane >> 4) * 4 + rg;
                    const float v = (m < M) ? acc[mi][ni][rg] : 0.f;
                    s += v; q += v * v;
                }
            s += __shfl_xor(s, 16); q += __shfl_xor(q, 16);
            s += __shfl_xor(s, 32); q += __shfl_xor(q, 32);
            if (lane < 16) {
                const int col = wc * 64 + ni * 16 + lane;
                atomicAdd(&st[col], s);
                atomicAdd(&st[256 + col], q);
            }
        }
    }
    if constexpr (ADOT) {
        #pragma unroll
        for (int mi = 0; mi < 4; ++mi) {
            float ps[4] = {0.f, 0.f, 0.f, 0.f};
            float pd[4] = {0.f, 0.f, 0.f, 0.f};
            #pragma unroll
            for (int ni = 0; ni < 4; ++ni) {
                const int col = wc * 64 + ni * 16 + (lane & 15);
                const float a_s = avs[col], a_d = avd[col];
                #pragma unroll
                for (int rg = 0; rg < 4; ++rg) {
                    ps[rg] += acc[mi][ni][rg] * a_s;
                    pd[rg] += acc[mi][ni][rg] * a_d;
                }
            }
            #pragma unroll
            for (int rg = 0; rg < 4; ++rg) {
                #pragma unroll
                for (int off = 1; off < 16; off <<= 1) {
                    ps[rg] += __shfl_xor(ps[rg], off);
                    pd[rg] += __shfl_xor(pd[rg], off);
                }
                const int m = m0 + wr * 64 + mi * 16 + (lane >> 4) * 4 + rg;
                if ((lane & 15) == 0 && m < M) {
                    atomicAdd(&a_src[m], ps[rg]);
                    atomicAdd(&a_dst[m], pd[rg]);
                }
            }
        }
    }
}

// per-column sum & sumsq of bf16 h into st[0..255], st[256..511].
__global__ void colstats_k(const unsigned short* __restrict__ h, float* st, int total4) {
    const int gid    = blockIdx.x * 256 + threadIdx.x;
    const int stride = gridDim.x * 256;
    float4 s = {0.f, 0.f, 0.f, 0.f}, q = {0.f, 0.f, 0.f, 0.f};
    for (int i = gid; i < total4; i += stride) {
        ushort4 v = ((const ushort4*)h)[i];
        float x0 = bf2f(v.x), x1 = bf2f(v.y), x2 = bf2f(v.z), x3 = bf2f(v.w);
        s.x += x0; s.y += x1; s.z += x2; s.w += x3;
        q.x += x0 * x0; q.y += x1 * x1; q.z += x2 * x2; q.w += x3 * x3;
    }
    __shared__ float red[2][4][64][4];
    const int wid = threadIdx.x >> 6, lane = threadIdx.x & 63;
    *(float4*)&red[0][wid][lane][0] = s;
    *(float4*)&red[1][wid][lane][0] = q;
    __syncthreads();
    if (wid == 0) {
        float4 s0 = *(float4*)&red[0][0][lane][0];
        float4 q0 = *(float4*)&red[1][0][lane][0];
        #pragma unroll
        for (int w = 1; w < 4; ++w) {
            float4 sw = *(float4*)&red[0][w][lane][0];
            float4 qw = *(float4*)&red[1][w][lane][0];
            s0.x += sw.x; s0.y += sw.y; s0.z += sw.z; s0.w += sw.w;
            q0.x += qw.x; q0.y += qw.y; q0.z += qw.z; q0.w += qw.w;
        }
        atomicAdd(&st[lane * 4 + 0], s0.x);
        atomicAdd(&st[lane * 4 + 1], s0.y);
        atomicAdd(&st[lane * 4 + 2], s0.z);
        atomicAdd(&st[lane * 4 + 3], s0.w);
        atomicAdd(&st[256 + lane * 4 + 0], q0.x);
        atomicAdd(&st[256 + lane * 4 + 1], q0.y);
        atomicAdd(&st[256 + lane * 4 + 2], q0.z);
        atomicAdd(&st[256 + lane * 4 + 3], q0.w);
    }
}

// Fused BN-finalize + BN-apply + ELU.
template<bool OUT_F32>
__global__ void bnelu_k(const unsigned short* __restrict__ h,
                        const float* __restrict__ st, const float* __restrict__ g,
                        const float* __restrict__ be, void* __restrict__ outp,
                        int total4, float invN) {
    const int gid    = blockIdx.x * 256 + threadIdx.x;
    const int stride = gridDim.x * 256;
    const int c      = (gid << 2) & 255;
    float sc[4], sh[4];
    #pragma unroll
    for (int j = 0; j < 4; ++j) {
        float mu  = st[c + j] * invN;
        float var = st[256 + c + j] * invN - mu * mu;
        float s   = g[c + j] * rsqrtf(var + 1e-5f);
        sc[j] = s;
        sh[j] = be[c + j] - mu * s;
    }
    for (int i = gid; i < total4; i += stride) {
        ushort4 v = ((const ushort4*)h)[i];
        float y0 = fmaf(bf2f(v.x), sc[0], sh[0]);
        float y1 = fmaf(bf2f(v.y), sc[1], sh[1]);
        float y2 = fmaf(bf2f(v.z), sc[2], sh[2]);
        float y3 = fmaf(bf2f(v.w), sc[3], sh[3]);
        y0 = y0 > 0.f ? y0 : expm1f(y0);
        y1 = y1 > 0.f ? y1 : expm1f(y1);
        y2 = y2 > 0.f ? y2 : expm1f(y2);
        y3 = y3 > 0.f ? y3 : expm1f(y3);
        if (OUT_F32) {
            float4 o; o.x = y0; o.y = y1; o.z = y2; o.w = y3;
            ((float4*)outp)[i] = o;
        } else {
            ushort4 o;
            o.x = f2bf(y0); o.y = f2bf(y1); o.z = f2bf(y2); o.w = f2bf(y3);
            ((ushort4*)outp)[i] = o;
        }
    }
}

DEV float lrelu(float e) { return e > 0.f ? e : 0.2f * e; }

// one wave per destination node: online max+sum, then x4-unrolled gather.
__global__ void gat_k(const unsigned short* __restrict__ xl, const float* __restrict__ a_src,
                      const float* __restrict__ a_dst, const int* __restrict__ csr,
                      const int* __restrict__ indptr, unsigned short* __restrict__ out, int N) {
    int d = (blockIdx.x * blockDim.x + threadIdx.x) >> 6;
    int lane = threadIdx.x & 63;
    if (d >= N) return;
    int beg = indptr[d], end = indptr[d + 1];
    float adst = a_dst[d];

    float m = -1e30f, s = 0.f;
    for (int i = beg + lane; i < end; i += 64) {
        float e  = lrelu(a_src[csr[i]] + adst);
        float nm = fmaxf(m, e);
        s = s * __expf(m - nm) + __expf(e - nm);
        m = nm;
    }
    float mx = m;
    #pragma unroll
    for (int off = 32; off; off >>= 1) mx = fmaxf(mx, __shfl_xor(mx, off));
    s *= __expf(m - mx);
    #pragma unroll
    for (int off = 32; off; off >>= 1) s += __shfl_xor(s, off);
    float inv = 1.f / (s + 1e-16f);

    float4 A0 = {0,0,0,0}, A1 = {0,0,0,0}, A2 = {0,0,0,0}, A3 = {0,0,0,0};
    int i = beg;
    for (; i + 4 <= end; i += 4) {
        int s0 = csr[i], s1 = csr[i+1], s2 = csr[i+2], s3 = csr[i+3];
        float w0 = __expf(lrelu(a_src[s0] + adst) - mx) * inv;
        float w1 = __expf(lrelu(a_src[s1] + adst) - mx) * inv;
        float w2 = __expf(lrelu(a_src[s2] + adst) - mx) * inv;
        float w3 = __expf(lrelu(a_src[s3] + adst) - mx) * inv;
        ushort4 v0 = *(const ushort4*)(xl + (size_t)s0 * 256 + lane * 4);
        ushort4 v1 = *(const ushort4*)(xl + (size_t)s1 * 256 + lane * 4);
        ushort4 v2 = *(const ushort4*)(xl + (size_t)s2 * 256 + lane * 4);
        ushort4 v3 = *(const ushort4*)(xl + (size_t)s3 * 256 + lane * 4);
        A0.x += w0 * bf2f(v0.x); A0.y += w0 * bf2f(v0.y); A0.z += w0 * bf2f(v0.z); A0.w += w0 * bf2f(v0.w);
        A1.x += w1 * bf2f(v1.x); A1.y += w1 * bf2f(v1.y); A1.z += w1 * bf2f(v1.z); A1.w += w1 * bf2f(v1.w);
        A2.x += w2 * bf2f(v2.x); A2.y += w2 * bf2f(v2.y); A2.z += w2 * bf2f(v2.z); A2.w += w2 * bf2f(v2.w);
        A3.x += w3 * bf2f(v3.x); A3.y += w3 * bf2f(v3.y); A3.z += w3 * bf2f(v3.z); A3.w += w3 * bf2f(v3.w);
    }
    for (; i < end; ++i) {
        int sidx = csr[i];
        float w = __expf(lrelu(a_src[sidx] + adst) - mx) * inv;
        ushort4 v = *(const ushort4*)(xl + (size_t)sidx * 256 + lane * 4);
        A0.x += w * bf2f(v.x); A0.y += w * bf2f(v.y);
        A0.z += w * bf2f(v.z); A0.w += w * bf2f(v.w);
    }
    ushort4 o;
    o.x = f2bf(A0.x + A1.x + A2.x + A3.x);
    o.y = f2bf(A0.y + A1.y + A2.y + A3.y);
    o.z = f2bf(A0.z + A1.z + A2.z + A3.z);
    o.w = f2bf(A0.w + A1.w + A2.w + A3.w);
    *(ushort4*)(out + (size_t)d * 256 + lane * 4) = o;
}

// ---- CSR build ----
__global__ void hist_k(const int* __restrict__ edges, int* deg, int E, int N) {
    int total = E + N;
    for (int i = blockIdx.x * blockDim.x + threadIdx.x; i < total;
         i += gridDim.x * blockDim.x) {
        int dd = (i < E) ? edges[E + i] : (i - E);
        atomicAdd(&deg[dd], 1);
    }
}

__global__ void scan1_k(const int* __restrict__ deg, int* iscan, int* bsum, int N) {
    int i = blockIdx.x * 256 + threadIdx.x;
    int lane = threadIdx.x & 63, wid = threadIdx.x >> 6;
    int v = (i < N) ? deg[i] : 0;
    #pragma unroll
    for (int off = 1; off < 64; off <<= 1) {
        int u = __shfl_up(v, off);
        if (lane >= off) v += u;
    }
    __shared__ int wsum[4];
    if (lane == 63) wsum[wid] = v;
    __syncthreads();
    #pragma unroll
    for (int w = 0; w < 3; ++w) if (wid > w) v += wsum[w];
    if (i < N) iscan[i] = v;
    if (threadIdx.x == 255) bsum[blockIdx.x] = v;
}

__global__ void scan2_k(int* bsum, int nb) {
    int t = threadIdx.x;
    int lane = t & 63, wid = t >> 6;
    int v = (t < nb) ? bsum[t] : 0;
    int orig = v;
    #pragma unroll
    for (int off = 1; off < 64; off <<= 1) {
        int u = __shfl_up(v, off);
        if (lane >= off) v += u;
    }
    __shared__ int wsum[4];
    if (lane == 63) wsum[wid] = v;
    __syncthreads();
    #pragma unroll
    for (int w = 0; w < 3; ++w) if (wid > w) v += wsum[w];
    if (t < nb) bsum[t] = v - orig;
}

__global__ void scan3copy_k(const int* __restrict__ iscan, const int* __restrict__ boff,
                            const int* __restrict__ deg, int* indptr, int* pos, int N) {
    int i = blockIdx.x * 256 + threadIdx.x;
    if (i < N) {
        int v = iscan[i] + boff[blockIdx.x];
        indptr[i + 1] = v;
        pos[i] = v - deg[i];
    }
    if (i == 0) indptr[0] = 0;
}

__global__ void scatter_k(const int* __restrict__ edges, int* pos, int* csr, int E, int N) {
    int total = E + N;
    for (int i = blockIdx.x * blockDim.x + threadIdx.x; i < total;
         i += gridDim.x * blockDim.x) {
        int s  = (i < E) ? edges[i]     : (i - E);
        int dd = (i < E) ? edges[E + i] : (i - E);
        int slot = atomicAdd(&pos[dd], 1);
        csr[slot] = s;
    }
}

// ---------------------------------------------------------------------------
extern "C" void kernel_launch(void* const* d_in, const int* in_sizes, int n_in,
                              void* d_out, int out_size, void* d_ws, size_t ws_size,
                              hipStream_t stream) {
    const float* x     = (const float*)d_in[0];
    const int*   edges = (const int*)d_in[1];
    const float* W1 = (const float*)d_in[2];
    const float* W2 = (const float*)d_in[4];
    const float* W3 = (const float*)d_in[6];
    const float* g1 = (const float*)d_in[8],  *be1 = (const float*)d_in[9];
    const float* g2 = (const float*)d_in[10], *be2 = (const float*)d_in[11];
    const float* g3 = (const float*)d_in[12], *be3 = (const float*)d_in[13];
    const float* Wg1 = (const float*)d_in[14];
    const float* as1 = (const float*)d_in[15], *ad1 = (const float*)d_in[16];
    const float* g4 = (const float*)d_in[18], *be4 = (const float*)d_in[19];
    const float* Wg2 = (const float*)d_in[20];
    const float* as2 = (const float*)d_in[21], *ad2 = (const float*)d_in[22];
    const float* g5 = (const float*)d_in[24], *be5 = (const float*)d_in[25];

    const int N    = out_size / 256;
    const int K1   = in_sizes[0] / N;
    const int E    = in_sizes[1] / 2;
    const int Etot = E + N;
    const int ks1  = (K1 + 63) / 64;
    const int ldb1 = ks1 * 64;                // B padded K (2624) = 82*32

    // workspace carve (256B aligned)
    char* p = (char*)d_ws;
    auto alloc = [&](size_t bytes) {
        char* r = p;
        p += (bytes + 255) & ~(size_t)255;
        return r;
    };
    unsigned short* W1T  = (unsigned short*)alloc((size_t)256 * ldb1 * 2);
    unsigned short* W2T  = (unsigned short*)alloc(256 * 256 * 2);
    unsigned short* W3T  = (unsigned short*)alloc(256 * 256 * 2);
    unsigned short* Wg1T = (unsigned short*)alloc(256 * 256 * 2);
    unsigned short* Wg2T = (unsigned short*)alloc(256 * 256 * 2);
    unsigned short* ha   = (unsigned short*)alloc((size_t)N * 256 * 2);
    unsigned short* hb   = (unsigned short*)alloc((size_t)N * 256 * 2);
    unsigned short* xl   = (unsigned short*)alloc((size_t)N * 256 * 2);
    char* zero_base = p;
    int*   deg    = (int*)alloc((size_t)N * 4);
    float* st     = (float*)alloc(5 * 512 * 4);
    float* asrc1  = (float*)alloc((size_t)N * 4);
    float* adst1  = (float*)alloc((size_t)N * 4);
    float* asrc2  = (float*)alloc((size_t)N * 4);
    float* adst2  = (float*)alloc((size_t)N * 4);
    size_t zero_bytes = (size_t)(p - zero_base);
    int*   iscan  = (int*)alloc((size_t)N * 4);
    int*   bsum   = (int*)alloc(1024);
    int*   indptr = (int*)alloc((size_t)(N + 1) * 4);
    int*   pos    = (int*)alloc((size_t)N * 4);
    int*   csr    = (int*)alloc((size_t)Etot * 4);
    (void)alloc(1 << 19);   // tail guard (benign OOB reads of last tile rows)
    float* out = (float*)d_out;

    const int nb = (N + 255) / 256;
    const int eg = (Etot + 255) / 256;
    const int gb = (N + 127) / 128;           // 391 blocks, 48KB LDS -> 3/CU
    const int t4 = N * 64;
    const float invN = 1.f / (float)N;

    hipMemsetAsync(zero_base, 0, zero_bytes, stream);

    // ---- graph CSR ----
    hist_k<<<eg, 256, 0, stream>>>(edges, deg, E, N);
    scan1_k<<<nb, 256, 0, stream>>>(deg, iscan, bsum, N);
    scan2_k<<<1, 256, 0, stream>>>(bsum, nb);
    scan3copy_k<<<nb, 256, 0, stream>>>(iscan, bsum, deg, indptr, pos, N);
    scatter_k<<<eg, 256, 0, stream>>>(edges, pos, csr, E, N);

    // ---- weight prep (weights only; x conversion fused into gemm1f) ----
    wprep_k<<<512, 256, 0, stream>>>(W1, W2, W3, Wg1, Wg2, W1T, K1, ldb1);

    // ---- layer 1: fused f32-A GEMM (+stats) -> BN+ELU ----
    gemm1f_k<<<gb, 512, 0, stream>>>(x, W1T, ha, st, N, K1, ldb1, (K1 + 31) / 32);
    bnelu_k<false><<<2048, 256, 0, stream>>>(ha, st, g1, be1, ha, t4, invN);

    // ---- layers 2,3 ----
    gemm_k<true, false><<<gb, 512, 0, stream>>>(ha, W2T, hb, st + 512, nullptr, nullptr,
                                                nullptr, nullptr, N, 256, 256, 8);
    bnelu_k<false><<<2048, 256, 0, stream>>>(hb, st + 512, g2, be2, hb, t4, invN);

    gemm_k<true, false><<<gb, 512, 0, stream>>>(hb, W3T, ha, st + 1024, nullptr, nullptr,
                                                nullptr, nullptr, N, 256, 256, 8);
    bnelu_k<false><<<2048, 256, 0, stream>>>(ha, st + 1024, g3, be3, ha, t4, invN);

    // ---- GAT layer 1 (adot fused into GEMM epilogue) ----
    gemm_k<false, true><<<gb, 512, 0, stream>>>(ha, Wg1T, xl, nullptr, as1, ad1,
                                                asrc1, adst1, N, 256, 256, 8);
    gat_k<<<(N + 3) / 4, 256, 0, stream>>>(xl, asrc1, adst1, csr, indptr, hb, N);
    colstats_k<<<1024, 256, 0, stream>>>(hb, st + 1536, t4);
    bnelu_k<false><<<2048, 256, 0, stream>>>(hb, st + 1536, g4, be4, hb, t4, invN);

    // ---- GAT layer 2 ----
    gemm_k<false, true><<<gb, 512, 0, stream>>>(hb, Wg2T, xl, nullptr, as2, ad2,
                                                asrc2, adst2, N, 256, 256, 8);
    gat_k<<<(N + 3) / 4, 256, 0, stream>>>(xl, asrc2, adst2, csr, indptr, ha, N);
    colstats_k<<<1024, 256, 0, stream>>>(ha, st + 2048, t4);
    bnelu_k<true><<<2048, 256, 0, stream>>>(ha, st + 2048, g5, be5, out, t4, invN);
}

// Round 15
// 890.560 us; speedup vs baseline: 1.3460x; 1.0768x over previous
//
#include <hip/hip_runtime.h>

#define DEV __device__ __forceinline__
#define AS1 __attribute__((address_space(1)))
#define AS3 __attribute__((address_space(3)))

typedef __attribute__((ext_vector_type(4))) float f32x4;
typedef __attribute__((ext_vector_type(8))) short short8;

DEV float bf2f(unsigned short u) {
    union { unsigned int i; float f; } c;
    c.i = ((unsigned int)u) << 16;
    return c.f;
}
DEV unsigned short f2bf(float f) {
    union { float f; unsigned int i; } c;
    c.f = f;
    unsigned int u = c.i;
    u += 0x7FFFu + ((u >> 16) & 1u);   // RTNE (finite values only here)
    return (unsigned short)(u >> 16);
}

// ---------------------------------------------------------------------------
// prep_k: x conversion + all weight transposes + zero-fill of accumulators.
//   blocks [0, XB_B):           x f32[M][K1] -> xb bf16[M][ldb1] (0-padded)
//   blocks [XB_B, XB_B+WB):     5 weight transposes (contiguous dst) AND
//                               zero-fill of [deg | st x5 | a_src/dst x2]
// ---------------------------------------------------------------------------
#define XB_B 2048
#define WB   1600
__global__ void prep_k(const float* __restrict__ x,
                       const float* __restrict__ W1, const float* __restrict__ W2,
                       const float* __restrict__ W3, const float* __restrict__ Wg1,
                       const float* __restrict__ Wg2,
                       unsigned short* __restrict__ xb,
                       unsigned short* __restrict__ WTbase,
                       int* __restrict__ zerop, int zerowords,
                       int M, int K1, int ldb1) {
    if (blockIdx.x < XB_B) {
        const int gpr = ldb1 >> 3;
        const long long total = (long long)M * gpr;
        for (long long g = blockIdx.x * (long long)blockDim.x + threadIdx.x; g < total;
             g += (long long)XB_B * blockDim.x) {
            const int row = (int)(g / gpr);
            const int c8  = (int)(g - (long long)row * gpr);
            const int k0  = c8 * 8;
            const float* src = x + (size_t)row * K1 + k0;
            unsigned int w[4];
            if (k0 + 8 <= K1) {
                f32x4 v0 = *(const f32x4*)(src);
                f32x4 v1 = *(const f32x4*)(src + 4);
                w[0] = (unsigned int)f2bf(v0[0]) | ((unsigned int)f2bf(v0[1]) << 16);
                w[1] = (unsigned int)f2bf(v0[2]) | ((unsigned int)f2bf(v0[3]) << 16);
                w[2] = (unsigned int)f2bf(v1[0]) | ((unsigned int)f2bf(v1[1]) << 16);
                w[3] = (unsigned int)f2bf(v1[2]) | ((unsigned int)f2bf(v1[3]) << 16);
            } else {
                unsigned short o[8];
                #pragma unroll
                for (int j = 0; j < 8; ++j) o[j] = (k0 + j < K1) ? f2bf(src[j]) : (unsigned short)0;
                w[0] = o[0] | ((unsigned int)o[1] << 16);
                w[1] = o[2] | ((unsigned int)o[3] << 16);
                w[2] = o[4] | ((unsigned int)o[5] << 16);
                w[3] = o[6] | ((unsigned int)o[7] << 16);
            }
            *(uint4*)(xb + (size_t)row * ldb1 + k0) = *(uint4*)w;
        }
    } else {
        const int w1n   = 256 * ldb1;
        const int total = w1n + 4 * 65536;
        for (int idx = (blockIdx.x - XB_B) * blockDim.x + threadIdx.x; idx < total;
             idx += WB * blockDim.x) {
            const float* W; int K, ldb, i;
            if (idx < w1n) { W = W1; K = K1; ldb = ldb1; i = idx; }
            else {
                int r = (idx - w1n) >> 16;
                i = (idx - w1n) & 65535;
                W = (r == 0) ? W2 : (r == 1) ? W3 : (r == 2) ? Wg1 : Wg2;
                K = 256; ldb = 256;
            }
            int n = i / ldb, k = i - n * ldb;
            WTbase[idx] = f2bf(k < K ? W[(size_t)k * 256 + n] : 0.f);
        }
        // zero-fill accumulation region (deg | st x5 | a_src/dst x2)
        for (int idx = (blockIdx.x - XB_B) * blockDim.x + threadIdx.x; idx < zerowords;
             idx += WB * blockDim.x)
            zerop[idx] = 0;
    }
}

// ---------------------------------------------------------------------------
// Unified bf16 GEMM (round 10, best measured): BM=128, BN=256, BK=32,
// 8 waves, depth-2 counted-vmcnt, 48 KB LDS -> 3 blocks/CU.
// ---------------------------------------------------------------------------
template<bool STATS, bool ADOT>
__launch_bounds__(512)
__global__ void gemm_k(const unsigned short* __restrict__ A,
                       const unsigned short* __restrict__ Bt,
                       unsigned short* __restrict__ C,
                       float* __restrict__ st,
                       const float* __restrict__ avs, const float* __restrict__ avd,
                       float* __restrict__ a_src, float* __restrict__ a_dst,
                       int M, int lda, int ldb, int ksteps)
{
    __shared__ __align__(16) unsigned short As[2][128 * 32];   // 2 x 8 KB
    __shared__ __align__(16) unsigned short Bs[2][256 * 32];   // 2 x 16 KB
    const int t    = threadIdx.x;
    const int wid  = t >> 6;       // 0..7
    const int lane = t & 63;
    const int wr   = wid >> 2;     // 0..1
    const int wc   = wid & 3;      // 0..3
    const int m0   = blockIdx.x * 128;

    f32x4 acc[4][4] = {};

    auto stage = [&](int buf, int ks) {
        const int k0 = ks * 32;
        {
            const int rr  = wid * 16 + (lane >> 2);
            const int csw = (lane & 3) ^ ((rr >> 1) & 3);
            __builtin_amdgcn_global_load_lds(
                (const AS1 void*)(A + (size_t)(m0 + rr) * lda + k0 + csw * 8),
                (AS3 void*)(&As[buf][wid * 16 * 32]), 16, 0, 0);
        }
        #pragma unroll
        for (int o = 0; o < 2; ++o) {
            const int rr  = wid * 32 + o * 16 + (lane >> 2);
            const int csw = (lane & 3) ^ ((rr >> 1) & 3);
            __builtin_amdgcn_global_load_lds(
                (const AS1 void*)(Bt + (size_t)rr * ldb + k0 + csw * 8),
                (AS3 void*)(&Bs[buf][(wid * 32 + o * 16) * 32]), 16, 0, 0);
        }
    };
    auto compute = [&](int buf) {
        short8 af[4], bfr[4];
        #pragma unroll
        for (int mi = 0; mi < 4; ++mi) {
            const int r   = wr * 64 + mi * 16 + (lane & 15);
            const int csw = (lane >> 4) ^ ((r >> 1) & 3);
            af[mi] = *(const short8*)(&As[buf][r * 32 + csw * 8]);
        }
        #pragma unroll
        for (int ni = 0; ni < 4; ++ni) {
            const int r   = wc * 64 + ni * 16 + (lane & 15);
            const int csw = (lane >> 4) ^ ((r >> 1) & 3);
            bfr[ni] = *(const short8*)(&Bs[buf][r * 32 + csw * 8]);
        }
        __builtin_amdgcn_s_setprio(1);
        #pragma unroll
        for (int mi = 0; mi < 4; ++mi)
            #pragma unroll
            for (int ni = 0; ni < 4; ++ni)
                acc[mi][ni] = __builtin_amdgcn_mfma_f32_16x16x32_bf16(
                    af[mi], bfr[ni], acc[mi][ni], 0, 0, 0);
        __builtin_amdgcn_s_setprio(0);
    };

    stage(0, 0);
    __builtin_amdgcn_sched_barrier(0);
    stage(1, 1);
    asm volatile("s_waitcnt vmcnt(3)" ::: "memory");
    __builtin_amdgcn_sched_barrier(0);
    __builtin_amdgcn_s_barrier();
    __builtin_amdgcn_sched_barrier(0);

    int cur = 0;
    for (int k = 0; k < ksteps; ++k) {
        compute(cur);
        if (k + 1 >= ksteps) break;
        __builtin_amdgcn_sched_barrier(0);
        __builtin_amdgcn_s_barrier();
        __builtin_amdgcn_sched_barrier(0);
        if (k + 2 < ksteps) {
            stage(cur, k + 2);
            asm volatile("s_waitcnt vmcnt(3)" ::: "memory");
        } else {
            asm volatile("s_waitcnt vmcnt(0)" ::: "memory");
        }
        __builtin_amdgcn_sched_barrier(0);
        __builtin_amdgcn_s_barrier();
        __builtin_amdgcn_sched_barrier(0);
        cur ^= 1;
    }

    #pragma unroll
    for (int mi = 0; mi < 4; ++mi) {
        #pragma unroll
        for (int ni = 0; ni < 4; ++ni) {
            const int col = wc * 64 + ni * 16 + (lane & 15);
            #pragma unroll
            for (int rg = 0; rg < 4; ++rg) {
                const int m = m0 + wr * 64 + mi * 16 + (lane >> 4) * 4 + rg;
                if (m < M)
                    C[(size_t)m * 256 + col] = f2bf(acc[mi][ni][rg]);
            }
        }
    }
    if constexpr (STATS) {
        #pragma unroll
        for (int ni = 0; ni < 4; ++ni) {
            float s = 0.f, q = 0.f;
            #pragma unroll
            for (int mi = 0; mi < 4; ++mi)
                #pragma unroll
                for (int rg = 0; rg < 4; ++rg) {
                    const int m = m0 + wr * 64 + mi * 16 + (lane >> 4) * 4 + rg;
                    const float v = (m < M) ? acc[mi][ni][rg] : 0.f;
                    s += v; q += v * v;
                }
            s += __shfl_xor(s, 16); q += __shfl_xor(q, 16);
            s += __shfl_xor(s, 32); q += __shfl_xor(q, 32);
            if (lane < 16) {
                const int col = wc * 64 + ni * 16 + lane;
                atomicAdd(&st[col], s);
                atomicAdd(&st[256 + col], q);
            }
        }
    }
    if constexpr (ADOT) {
        #pragma unroll
        for (int mi = 0; mi < 4; ++mi) {
            float ps[4] = {0.f, 0.f, 0.f, 0.f};
            float pd[4] = {0.f, 0.f, 0.f, 0.f};
            #pragma unroll
            for (int ni = 0; ni < 4; ++ni) {
                const int col = wc * 64 + ni * 16 + (lane & 15);
                const float a_s = avs[col], a_d = avd[col];
                #pragma unroll
                for (int rg = 0; rg < 4; ++rg) {
                    ps[rg] += acc[mi][ni][rg] * a_s;
                    pd[rg] += acc[mi][ni][rg] * a_d;
                }
            }
            #pragma unroll
            for (int rg = 0; rg < 4; ++rg) {
                #pragma unroll
                for (int off = 1; off < 16; off <<= 1) {
                    ps[rg] += __shfl_xor(ps[rg], off);
                    pd[rg] += __shfl_xor(pd[rg], off);
                }
                const int m = m0 + wr * 64 + mi * 16 + (lane >> 4) * 4 + rg;
                if ((lane & 15) == 0 && m < M) {
                    atomicAdd(&a_src[m], ps[rg]);
                    atomicAdd(&a_dst[m], pd[rg]);
                }
            }
        }
    }
}

// per-column sum & sumsq of bf16 h into st[0..255], st[256..511].
__global__ void colstats_k(const unsigned short* __restrict__ h, float* st, int total4) {
    const int gid    = blockIdx.x * 256 + threadIdx.x;
    const int stride = gridDim.x * 256;
    float4 s = {0.f, 0.f, 0.f, 0.f}, q = {0.f, 0.f, 0.f, 0.f};
    for (int i = gid; i < total4; i += stride) {
        ushort4 v = ((const ushort4*)h)[i];
        float x0 = bf2f(v.x), x1 = bf2f(v.y), x2 = bf2f(v.z), x3 = bf2f(v.w);
        s.x += x0; s.y += x1; s.z += x2; s.w += x3;
        q.x += x0 * x0; q.y += x1 * x1; q.z += x2 * x2; q.w += x3 * x3;
    }
    __shared__ float red[2][4][64][4];
    const int wid = threadIdx.x >> 6, lane = threadIdx.x & 63;
    *(float4*)&red[0][wid][lane][0] = s;
    *(float4*)&red[1][wid][lane][0] = q;
    __syncthreads();
    if (wid == 0) {
        float4 s0 = *(float4*)&red[0][0][lane][0];
        float4 q0 = *(float4*)&red[1][0][lane][0];
        #pragma unroll
        for (int w = 1; w < 4; ++w) {
            float4 sw = *(float4*)&red[0][w][lane][0];
            float4 qw = *(float4*)&red[1][w][lane][0];
            s0.x += sw.x; s0.y += sw.y; s0.z += sw.z; s0.w += sw.w;
            q0.x += qw.x; q0.y += qw.y; q0.z += qw.z; q0.w += qw.w;
        }
        atomicAdd(&st[lane * 4 + 0], s0.x);
        atomicAdd(&st[lane * 4 + 1], s0.y);
        atomicAdd(&st[lane * 4 + 2], s0.z);
        atomicAdd(&st[lane * 4 + 3], s0.w);
        atomicAdd(&st[256 + lane * 4 + 0], q0.x);
        atomicAdd(&st[256 + lane * 4 + 1], q0.y);
        atomicAdd(&st[256 + lane * 4 + 2], q0.z);
        atomicAdd(&st[256 + lane * 4 + 3], q0.w);
    }
}

// Fused BN-finalize + BN-apply + ELU.
template<bool OUT_F32>
__global__ void bnelu_k(const unsigned short* __restrict__ h,
                        const float* __restrict__ st, const float* __restrict__ g,
                        const float* __restrict__ be, void* __restrict__ outp,
                        int total4, float invN) {
    const int gid    = blockIdx.x * 256 + threadIdx.x;
    const int stride = gridDim.x * 256;
    const int c      = (gid << 2) & 255;
    float sc[4], sh[4];
    #pragma unroll
    for (int j = 0; j < 4; ++j) {
        float mu  = st[c + j] * invN;
        float var = st[256 + c + j] * invN - mu * mu;
        float s   = g[c + j] * rsqrtf(var + 1e-5f);
        sc[j] = s;
        sh[j] = be[c + j] - mu * s;
    }
    for (int i = gid; i < total4; i += stride) {
        ushort4 v = ((const ushort4*)h)[i];
        float y0 = fmaf(bf2f(v.x), sc[0], sh[0]);
        float y1 = fmaf(bf2f(v.y), sc[1], sh[1]);
        float y2 = fmaf(bf2f(v.z), sc[2], sh[2]);
        float y3 = fmaf(bf2f(v.w), sc[3], sh[3]);
        y0 = y0 > 0.f ? y0 : expm1f(y0);
        y1 = y1 > 0.f ? y1 : expm1f(y1);
        y2 = y2 > 0.f ? y2 : expm1f(y2);
        y3 = y3 > 0.f ? y3 : expm1f(y3);
        if (OUT_F32) {
            float4 o; o.x = y0; o.y = y1; o.z = y2; o.w = y3;
            ((float4*)outp)[i] = o;
        } else {
            ushort4 o;
            o.x = f2bf(y0); o.y = f2bf(y1); o.z = f2bf(y2); o.w = f2bf(y3);
            ((ushort4*)outp)[i] = o;
        }
    }
}

DEV float lrelu(float e) { return e > 0.f ? e : 0.2f * e; }

// one wave per destination node: online max+sum, then x4-unrolled gather.
__global__ void gat_k(const unsigned short* __restrict__ xl, const float* __restrict__ a_src,
                      const float* __restrict__ a_dst, const int* __restrict__ csr,
                      const int* __restrict__ indptr, unsigned short* __restrict__ out, int N) {
    int d = (blockIdx.x * blockDim.x + threadIdx.x) >> 6;
    int lane = threadIdx.x & 63;
    if (d >= N) return;
    int beg = indptr[d], end = indptr[d + 1];
    float adst = a_dst[d];

    float m = -1e30f, s = 0.f;
    for (int i = beg + lane; i < end; i += 64) {
        float e  = lrelu(a_src[csr[i]] + adst);
        float nm = fmaxf(m, e);
        s = s * __expf(m - nm) + __expf(e - nm);
        m = nm;
    }
    float mx = m;
    #pragma unroll
    for (int off = 32; off; off >>= 1) mx = fmaxf(mx, __shfl_xor(mx, off));
    s *= __expf(m - mx);
    #pragma unroll
    for (int off = 32; off; off >>= 1) s += __shfl_xor(s, off);
    float inv = 1.f / (s + 1e-16f);

    float4 A0 = {0,0,0,0}, A1 = {0,0,0,0}, A2 = {0,0,0,0}, A3 = {0,0,0,0};
    int i = beg;
    for (; i + 4 <= end; i += 4) {
        int s0 = csr[i], s1 = csr[i+1], s2 = csr[i+2], s3 = csr[i+3];
        float w0 = __expf(lrelu(a_src[s0] + adst) - mx) * inv;
        float w1 = __expf(lrelu(a_src[s1] + adst) - mx) * inv;
        float w2 = __expf(lrelu(a_src[s2] + adst) - mx) * inv;
        float w3 = __expf(lrelu(a_src[s3] + adst) - mx) * inv;
        ushort4 v0 = *(const ushort4*)(xl + (size_t)s0 * 256 + lane * 4);
        ushort4 v1 = *(const ushort4*)(xl + (size_t)s1 * 256 + lane * 4);
        ushort4 v2 = *(const ushort4*)(xl + (size_t)s2 * 256 + lane * 4);
        ushort4 v3 = *(const ushort4*)(xl + (size_t)s3 * 256 + lane * 4);
        A0.x += w0 * bf2f(v0.x); A0.y += w0 * bf2f(v0.y); A0.z += w0 * bf2f(v0.z); A0.w += w0 * bf2f(v0.w);
        A1.x += w1 * bf2f(v1.x); A1.y += w1 * bf2f(v1.y); A1.z += w1 * bf2f(v1.z); A1.w += w1 * bf2f(v1.w);
        A2.x += w2 * bf2f(v2.x); A2.y += w2 * bf2f(v2.y); A2.z += w2 * bf2f(v2.z); A2.w += w2 * bf2f(v2.w);
        A3.x += w3 * bf2f(v3.x); A3.y += w3 * bf2f(v3.y); A3.z += w3 * bf2f(v3.z); A3.w += w3 * bf2f(v3.w);
    }
    for (; i < end; ++i) {
        int sidx = csr[i];
        float w = __expf(lrelu(a_src[sidx] + adst) - mx) * inv;
        ushort4 v = *(const ushort4*)(xl + (size_t)sidx * 256 + lane * 4);
        A0.x += w * bf2f(v.x); A0.y += w * bf2f(v.y);
        A0.z += w * bf2f(v.z); A0.w += w * bf2f(v.w);
    }
    ushort4 o;
    o.x = f2bf(A0.x + A1.x + A2.x + A3.x);
    o.y = f2bf(A0.y + A1.y + A2.y + A3.y);
    o.z = f2bf(A0.z + A1.z + A2.z + A3.z);
    o.w = f2bf(A0.w + A1.w + A2.w + A3.w);
    *(ushort4*)(out + (size_t)d * 256 + lane * 4) = o;
}

// ---- CSR build ----
__global__ void hist_k(const int* __restrict__ edges, int* deg, int E, int N) {
    int total = E + N;
    for (int i = blockIdx.x * blockDim.x + threadIdx.x; i < total;
         i += gridDim.x * blockDim.x) {
        int dd = (i < E) ? edges[E + i] : (i - E);
        atomicAdd(&deg[dd], 1);
    }
}

__global__ void scan1_k(const int* __restrict__ deg, int* iscan, int* bsum, int N) {
    int i = blockIdx.x * 256 + threadIdx.x;
    int lane = threadIdx.x & 63, wid = threadIdx.x >> 6;
    int v = (i < N) ? deg[i] : 0;
    #pragma unroll
    for (int off = 1; off < 64; off <<= 1) {
        int u = __shfl_up(v, off);
        if (lane >= off) v += u;
    }
    __shared__ int wsum[4];
    if (lane == 63) wsum[wid] = v;
    __syncthreads();
    #pragma unroll
    for (int w = 0; w < 3; ++w) if (wid > w) v += wsum[w];
    if (i < N) iscan[i] = v;
    if (threadIdx.x == 255) bsum[blockIdx.x] = v;
}

// indptr[i+1] = iscan[i] + (sum of bsum[0..blockIdx.x-1]); pos[i] = indptr[i].
// Block offset computed in-block (nb <= 256): replaces the old scan2 kernel.
__global__ void scan3copy_k(const int* __restrict__ iscan, const int* __restrict__ bsum,
                            const int* __restrict__ deg, int* indptr, int* pos,
                            int N, int nb) {
    const int t = threadIdx.x;
    int v = (t < blockIdx.x && t < nb) ? bsum[t] : 0;
    const int lane = t & 63, wid = t >> 6;
    #pragma unroll
    for (int off = 32; off; off >>= 1) v += __shfl_xor(v, off);
    __shared__ int wsum[4];
    if (lane == 0) wsum[wid] = v;
    __syncthreads();
    const int boff = wsum[0] + wsum[1] + wsum[2] + wsum[3];
    int i = blockIdx.x * 256 + t;
    if (i < N) {
        int val = iscan[i] + boff;
        indptr[i + 1] = val;
        pos[i] = val - deg[i];
    }
    if (i == 0) indptr[0] = 0;
}

__global__ void scatter_k(const int* __restrict__ edges, int* pos, int* csr, int E, int N) {
    int total = E + N;
    for (int i = blockIdx.x * blockDim.x + threadIdx.x; i < total;
         i += gridDim.x * blockDim.x) {
        int s  = (i < E) ? edges[i]     : (i - E);
        int dd = (i < E) ? edges[E + i] : (i - E);
        int slot = atomicAdd(&pos[dd], 1);
        csr[slot] = s;
    }
}

// ---------------------------------------------------------------------------
extern "C" void kernel_launch(void* const* d_in, const int* in_sizes, int n_in,
                              void* d_out, int out_size, void* d_ws, size_t ws_size,
                              hipStream_t stream) {
    const float* x     = (const float*)d_in[0];
    const int*   edges = (const int*)d_in[1];
    const float* W1 = (const float*)d_in[2];
    const float* W2 = (const float*)d_in[4];
    const float* W3 = (const float*)d_in[6];
    const float* g1 = (const float*)d_in[8],  *be1 = (const float*)d_in[9];
    const float* g2 = (const float*)d_in[10], *be2 = (const float*)d_in[11];
    const float* g3 = (const float*)d_in[12], *be3 = (const float*)d_in[13];
    const float* Wg1 = (const float*)d_in[14];
    const float* as1 = (const float*)d_in[15], *ad1 = (const float*)d_in[16];
    const float* g4 = (const float*)d_in[18], *be4 = (const float*)d_in[19];
    const float* Wg2 = (const float*)d_in[20];
    const float* as2 = (const float*)d_in[21], *ad2 = (const float*)d_in[22];
    const float* g5 = (const float*)d_in[24], *be5 = (const float*)d_in[25];

    const int N    = out_size / 256;
    const int K1   = in_sizes[0] / N;
    const int E    = in_sizes[1] / 2;
    const int Etot = E + N;
    const int ks1  = (K1 + 63) / 64;
    const int ldb1 = ks1 * 64;                // padded K (2624), 32 | ldb1

    // workspace carve (256B aligned)
    char* p = (char*)d_ws;
    auto alloc = [&](size_t bytes) {
        char* r = p;
        p += (bytes + 255) & ~(size_t)255;
        return r;
    };
    unsigned short* W1T  = (unsigned short*)alloc((size_t)256 * ldb1 * 2);
    unsigned short* W2T  = (unsigned short*)alloc(256 * 256 * 2);
    unsigned short* W3T  = (unsigned short*)alloc(256 * 256 * 2);
    unsigned short* Wg1T = (unsigned short*)alloc(256 * 256 * 2);
    unsigned short* Wg2T = (unsigned short*)alloc(256 * 256 * 2);
    unsigned short* xb   = (unsigned short*)alloc((size_t)N * ldb1 * 2);
    unsigned short* ha   = (unsigned short*)alloc((size_t)N * 256 * 2);
    unsigned short* hb   = (unsigned short*)alloc((size_t)N * 256 * 2);
    unsigned short* xl   = (unsigned short*)alloc((size_t)N * 256 * 2);
    char* zero_base = p;
    int*   deg    = (int*)alloc((size_t)N * 4);
    float* st     = (float*)alloc(5 * 512 * 4);
    float* asrc1  = (float*)alloc((size_t)N * 4);
    float* adst1  = (float*)alloc((size_t)N * 4);
    float* asrc2  = (float*)alloc((size_t)N * 4);
    float* adst2  = (float*)alloc((size_t)N * 4);
    size_t zero_bytes = (size_t)(p - zero_base);
    int*   iscan  = (int*)alloc((size_t)N * 4);
    int*   bsum   = (int*)alloc(1024);
    int*   indptr = (int*)alloc((size_t)(N + 1) * 4);
    int*   pos    = (int*)alloc((size_t)N * 4);
    int*   csr    = (int*)alloc((size_t)Etot * 4);
    (void)alloc(1 << 19);   // tail guard (benign OOB reads of last tile rows)
    float* out = (float*)d_out;

    const int nb = (N + 255) / 256;
    const int eg = (Etot + 255) / 256;
    const int gb = (N + 127) / 128;           // 391 blocks, 48KB LDS -> 3/CU
    const int t4 = N * 64;
    const float invN = 1.f / (float)N;

    // ---- prep: x conversion + weight transposes + zero-fill (no memset) ----
    prep_k<<<XB_B + WB, 256, 0, stream>>>(x, W1, W2, W3, Wg1, Wg2, xb, W1T,
                                          (int*)zero_base, (int)(zero_bytes / 4),
                                          N, K1, ldb1);

    // ---- graph CSR (deg zeroed by prep_k) ----
    hist_k<<<eg, 256, 0, stream>>>(edges, deg, E, N);
    scan1_k<<<nb, 256, 0, stream>>>(deg, iscan, bsum, N);
    scan3copy_k<<<nb, 256, 0, stream>>>(iscan, bsum, deg, indptr, pos, N, nb);
    scatter_k<<<eg, 256, 0, stream>>>(edges, pos, csr, E, N);

    // ---- layer 1: GEMM (+stats) -> BN+ELU ----
    gemm_k<true, false><<<gb, 512, 0, stream>>>(xb, W1T, ha, st, nullptr, nullptr,
                                                nullptr, nullptr, N, ldb1, ldb1, ldb1 / 32);
    bnelu_k<false><<<2048, 256, 0, stream>>>(ha, st, g1, be1, ha, t4, invN);

    // ---- layers 2,3 ----
    gemm_k<true, false><<<gb, 512, 0, stream>>>(ha, W2T, hb, st + 512, nullptr, nullptr,
                                                nullptr, nullptr, N, 256, 256, 8);
    bnelu_k<false><<<2048, 256, 0, stream>>>(hb, st + 512, g2, be2, hb, t4, invN);

    gemm_k<true, false><<<gb, 512, 0, stream>>>(hb, W3T, ha, st + 1024, nullptr, nullptr,
                                                nullptr, nullptr, N, 256, 256, 8);
    bnelu_k<false><<<2048, 256, 0, stream>>>(ha, st + 1024, g3, be3, ha, t4, invN);

    // ---- GAT layer 1 (adot fused into GEMM epilogue) ----
    gemm_k<false, true><<<gb, 512, 0, stream>>>(ha, Wg1T, xl, nullptr, as1, ad1,
                                                asrc1, adst1, N, 256, 256, 8);
    gat_k<<<(N + 3) / 4, 256, 0, stream>>>(xl, asrc1, adst1, csr, indptr, hb, N);
    colstats_k<<<1024, 256, 0, stream>>>(hb, st + 1536, t4);
    bnelu_k<false><<<2048, 256, 0, stream>>>(hb, st + 1536, g4, be4, hb, t4, invN);

    // ---- GAT layer 2 ----
    gemm_k<false, true><<<gb, 512, 0, stream>>>(hb, Wg2T, xl, nullptr, as2, ad2,
                                                asrc2, adst2, N, 256, 256, 8);
    gat_k<<<(N + 3) / 4, 256, 0, stream>>>(xl, asrc2, adst2, csr, indptr, ha, N);
    colstats_k<<<1024, 256, 0, stream>>>(ha, st + 2048, t4);
    bnelu_k<true><<<2048, 256, 0, stream>>>(ha, st + 2048, g5, be5, out, t4, invN);
}